// Round 2
// baseline (726.671 us; speedup 1.0000x reference)
//
#include <hip/hip_runtime.h>

typedef unsigned short u16;
typedef unsigned char u8;
typedef unsigned int u32;
typedef unsigned long long u64;
typedef short short8 __attribute__((ext_vector_type(8)));
typedef float f32x4 __attribute__((ext_vector_type(4)));
typedef float f32x2 __attribute__((ext_vector_type(2)));

#define NN   100000
#define EE   1600000
#define ETOT (EE + NN)
#define NG   64
#define WSTR 136   // padded LDS row stride in bf16 elems (128 + 8)
#define SCANB 98   // ceil(NN / 1024)
#define EPB  4096  // edges per block in k_deg/k_fill

// ---------------- static device workspace ----------------
constexpr size_t AL256(size_t x) { return (x + 255) & ~(size_t)255; }
constexpr size_t OFF_FLAG   = 0;                                   // [0]=bf16 [1]=wide
constexpr size_t OFF_BSUM   = AL256(OFF_FLAG + 256);
constexpr size_t OFF_ROWPTR = AL256(OFF_BSUM + 128 * 4);
constexpr size_t OFF_DEG    = AL256(OFF_ROWPTR + (size_t)(NN + 1) * 4);  // degree, then fill-cursor
constexpr size_t OFF_COL    = AL256(OFF_DEG + (size_t)NN * 4);
constexpr size_t OFF_ALS    = AL256(OFF_COL + (size_t)ETOT * 4);
constexpr size_t OFF_ALD    = AL256(OFF_ALS + (size_t)NN * 4 * 4);
constexpr size_t OFF_GSUM   = AL256(OFF_ALD + (size_t)NN * 4 * 4);
constexpr size_t OFF_GKEY   = AL256(OFF_GSUM + (size_t)NG * 128 * 4);
constexpr size_t OFF_GCNT   = AL256(OFF_GKEY + (size_t)NG * 128 * 4);
constexpr size_t OFF_H      = AL256(OFF_GCNT + (size_t)NG * 4);          // bf16 h
constexpr size_t OFF_HPB    = AL256(OFF_H + (size_t)NN * 128 * 2);       // fp8-e4m3 hp
constexpr size_t WS_TOTAL   = AL256(OFF_HPB + (size_t)NN * 128 * 1);

__device__ u64 g_ws[WS_TOTAL / 8];

__device__ __forceinline__ char* wsp() { return (char*)g_ws; }
#define WS_FLAG   ((int*)(wsp() + OFF_FLAG))
#define WS_BSUM   ((int*)(wsp() + OFF_BSUM))
#define WS_ROWPTR ((int*)(wsp() + OFF_ROWPTR))
#define WS_DEG    ((int*)(wsp() + OFF_DEG))
#define WS_COL    ((int*)(wsp() + OFF_COL))
#define WS_ALS    ((float*)(wsp() + OFF_ALS))
#define WS_ALD    ((float*)(wsp() + OFF_ALD))
#define WS_GSUM   ((float*)(wsp() + OFF_GSUM))
#define WS_GKEY   ((u32*)(wsp() + OFF_GKEY))
#define WS_GCNT   ((int*)(wsp() + OFF_GCNT))
#define WS_H      ((u16*)(wsp() + OFF_H))
#define WS_HPB    ((u8*)(wsp() + OFF_HPB))

__device__ __forceinline__ float b2f(u16 u) { return __uint_as_float(((u32)u) << 16); }
__device__ __forceinline__ float b2f_lo(u32 u) { return __uint_as_float(u << 16); }
__device__ __forceinline__ float b2f_hi(u32 u) { return __uint_as_float(u & 0xffff0000u); }
__device__ __forceinline__ u16 f2bf(float f) {
    u32 u = __float_as_uint(f);
    return (u16)((u + 0x7fffu + ((u >> 16) & 1u)) >> 16);
}
__device__ __forceinline__ float ldf(const void* p, int i, int bf) {
    return bf ? b2f(((const u16*)p)[i]) : ((const float*)p)[i];
}
__device__ __forceinline__ int ldint(const int* p, long long i, int wide) {
    return wide ? p[i * 2] : p[(size_t)i];
}
__device__ __forceinline__ u32 fkey(float f) {
    u32 u = __float_as_uint(f);
    return (u >> 31) ? ~u : (u | 0x80000000u);
}
__device__ __forceinline__ float funkey(u32 k) {
    u32 u = (k & 0x80000000u) ? (k & 0x7fffffffu) : ~k;
    return __uint_as_float(u);
}

// ---------------- zero scratch + dtype probes (fused) ----------------
__global__ __launch_bounds__(256) void k_zero(const void* __restrict__ x,
                                              const int* __restrict__ ei) {
    if (blockIdx.x == 0 && threadIdx.x < 64) {
        int t = threadIdx.x;
        const u16* p = (const u16*)x;
        u16 u = p[t * 2];
        int e = (u >> 7) & 0xff;
        int ok = ((u & 0x7fffu) == 0) || (e >= 0x60 && e <= 0x9f);
        u64 m1 = __ballot(ok);
        int z = (ei[t * 2 + 1] == 0);
        u64 m2 = __ballot(z);
        if (t == 0) {
            WS_FLAG[0] = (__popcll(m1) >= 48) ? 1 : 0;
            WS_FLAG[1] = (__popcll(m2) >= 56) ? 1 : 0;
        }
    }
    int i = blockIdx.x * 256 + threadIdx.x;
    if (i < NN) WS_DEG[i] = 0;
    if (i < NG * 128) { WS_GSUM[i] = 0.f; WS_GKEY[i] = 0u; }
    if (i < NG) WS_GCNT[i] = 0;
}

// ---- CSR 1: degree count via global atomics (L2-resident counters) ----
__global__ __launch_bounds__(256) void k_deg(const int* __restrict__ ei) {
    int wide = WS_FLAG[1];
    int e0 = blockIdx.x * EPB + threadIdx.x;
#pragma unroll
    for (int j = 0; j < 16; j++) {
        int e = e0 + j * 256;
        if (e < ETOT) {
            int s, d;
            if (e < EE) {
                if (wide) { s = ((const int2*)ei)[e].x; d = ((const int2*)ei)[(size_t)EE + e].x; }
                else      { s = ei[e];                  d = ei[(size_t)EE + e]; }
            } else { s = e - EE; d = s; }
            if ((u32)s < NN && (u32)d < NN) atomicAdd(&WS_DEG[d], 1);
        }
    }
}

// ---- CSR 2: per-1024-block exclusive scan of degrees; zero DEG for cursor reuse ----
__global__ __launch_bounds__(1024) void k_scan1() {
    __shared__ int sdat[1024];
    int b = blockIdx.x, t = threadIdx.x;
    int i = b * 1024 + t;
    int v = 0;
    if (i < NN) { v = WS_DEG[i]; WS_DEG[i] = 0; }
    sdat[t] = v;
    __syncthreads();
    for (int off = 1; off < 1024; off <<= 1) {
        int u = 0;
        if (t >= off) u = sdat[t - off];
        __syncthreads();
        if (t >= off) sdat[t] += u;
        __syncthreads();
    }
    if (i <= NN) WS_ROWPTR[i] = sdat[t] - v;   // local exclusive prefix (i==NN: block 97 tail)
    if (t == 1023) WS_BSUM[b] = sdat[1023];
}

// ---- CSR 3: finalize rowptr with block-sum prefix (redundant 98-wide scan per block) ----
__global__ __launch_bounds__(1024) void k_fin() {
    __shared__ int sb[128];
    int b = blockIdx.x, t = threadIdx.x;
    if (t < 128) sb[t] = (t < SCANB) ? WS_BSUM[t] : 0;
    __syncthreads();
    for (int off = 1; off < 128; off <<= 1) {
        int u = 0;
        if (t < 128 && t >= off) u = sb[t - off];
        __syncthreads();
        if (t < 128 && t >= off) sb[t] += u;
        __syncthreads();
    }
    if (b > 0) {
        int add = sb[b - 1];
        int i = b * 1024 + t;
        if (i <= NN) WS_ROWPTR[i] += add;
    }
}

// ---- CSR 4: place edges; DEG (zeroed) serves as per-node cursor ----
__global__ __launch_bounds__(256) void k_fill(const int* __restrict__ ei) {
    int wide = WS_FLAG[1];
    int e0 = blockIdx.x * EPB + threadIdx.x;
#pragma unroll
    for (int j = 0; j < 16; j++) {
        int e = e0 + j * 256;
        if (e < ETOT) {
            int s, d;
            if (e < EE) {
                if (wide) { s = ((const int2*)ei)[e].x; d = ((const int2*)ei)[(size_t)EE + e].x; }
                else      { s = ei[e];                  d = ei[(size_t)EE + e]; }
            } else { s = e - EE; d = s; }
            if ((u32)s < NN && (u32)d < NN) {
                int pos = WS_ROWPTR[d] + atomicAdd(&WS_DEG[d], 1);
                WS_COL[pos] = s;
            }
        }
    }
}

// ---------------- node feature MLP: h = gelu(x @ Wp + bp), bf16 out ----------------
__global__ __launch_bounds__(128) void k_proj(const void* __restrict__ x,
                                              const void* __restrict__ Wp,
                                              const void* __restrict__ bp) {
    __shared__ float sW[16 * 128];
    int t = threadIdx.x;
    int bf = WS_FLAG[0];
    for (int i = t; i < 16 * 128; i += 128) sW[i] = ldf(Wp, i, bf);
    __syncthreads();
    float bj = ldf(bp, t, bf);
    for (int n = blockIdx.x; n < NN; n += gridDim.x) {
        float acc = bj;
#pragma unroll
        for (int k = 0; k < 16; k++)
            acc = fmaf(ldf(x, n * 16 + k, bf), sW[k * 128 + t], acc);
        float g = 0.5f * acc * (1.0f + erff(acc * 0.70710678118654752f));
        WS_H[(size_t)n * 128 + t] = f2bf(g);
    }
}

// --- hp = h @ Wg via MFMA 16x16x32 bf16; fp8-e4m3 hp out; fused als/ald ---
__global__ __launch_bounds__(256) void k_gemm(const void* __restrict__ Wg,
                                              const void* __restrict__ a_s,
                                              const void* __restrict__ a_d) {
    __shared__ __align__(16) u16 sWt[128 * WSTR];   // W transposed, padded
    __shared__ __align__(16) u16 sH[16 * WSTR];     // 16 H rows (bf16), padded
    int t = threadIdx.x;
    int bf = WS_FLAG[0];
    for (int idx = t; idx < 128 * 128; idx += 256) {
        int k = idx >> 7, n = idx & 127;
        sWt[n * WSTR + k] = bf ? ((const u16*)Wg)[idx] : f2bf(((const float*)Wg)[idx]);
    }
    __syncthreads();
    int wv = t >> 6, lane = t & 63;
    int n0 = wv * 32;                 // wave wv owns cols 32wv..32wv+31 == head wv
    int quad = lane >> 4, m16 = lane & 15;
    float as0v = ldf(a_s, n0 + m16, bf),      as1v = ldf(a_s, n0 + 16 + m16, bf);
    float ad0v = ldf(a_d, n0 + m16, bf),      ad1v = ldf(a_d, n0 + 16 + m16, bf);
    short8 bfr[2][4];
#pragma unroll
    for (int nt = 0; nt < 2; nt++) {
        int n = n0 + nt * 16 + m16;
#pragma unroll
        for (int ks = 0; ks < 4; ks++)
            bfr[nt][ks] = *(const short8*)&sWt[n * WSTR + ks * 32 + quad * 8];
    }
    u8* hp = WS_HPB;
    const u32* h32 = (const u32*)WS_H;
    u32* sH32 = (u32*)sH;
    for (int m0 = blockIdx.x * 16; m0 < NN; m0 += gridDim.x * 16) {
        __syncthreads();
        for (int idx = t; idx < 16 * 64; idx += 256) {
            int r = idx >> 6, c2 = idx & 63;
            sH32[r * 68 + c2] = h32[(size_t)(m0 + r) * 64 + c2];  // 68 = WSTR/2
        }
        __syncthreads();
        f32x4 acc0 = {0.f, 0.f, 0.f, 0.f};
        f32x4 acc1 = {0.f, 0.f, 0.f, 0.f};
#pragma unroll
        for (int ks = 0; ks < 4; ks++) {
            short8 af = *(const short8*)&sH[m16 * WSTR + ks * 32 + quad * 8];
            acc0 = __builtin_amdgcn_mfma_f32_16x16x32_bf16(af, bfr[0][ks], acc0, 0, 0, 0);
            acc1 = __builtin_amdgcn_mfma_f32_16x16x32_bf16(af, bfr[1][ks], acc1, 0, 0, 0);
        }
        // D: col = lane&15, row = quad*4 + reg
#pragma unroll
        for (int r = 0; r < 4; r++) {
            size_t row = (size_t)(m0 + quad * 4 + r) * 128;
            u32 pk8 = (u32)__builtin_amdgcn_cvt_pk_fp8_f32(acc0[r], acc1[r], 0, false);
            hp[row + n0 + m16]      = (u8)(pk8 & 0xff);
            hp[row + n0 + 16 + m16] = (u8)((pk8 >> 8) & 0xff);
            float ps = acc0[r] * as0v + acc1[r] * as1v;
            float pd = acc0[r] * ad0v + acc1[r] * ad1v;
#pragma unroll
            for (int m = 1; m <= 8; m <<= 1) {
                ps += __shfl_xor(ps, m);
                pd += __shfl_xor(pd, m);
            }
            if (m16 == 0) {
                int nrow = m0 + quad * 4 + r;
                WS_ALS[nrow * 4 + wv] = ps;
                WS_ALD[nrow * 4 + wv] = pd;
            }
        }
    }
}

// ------- GAT: 1 node/wave; u32 gathers = 2 edges/instr (halves of wave alternate) -------
// R1: VALUBusy 52% co-limits load issue. Now per 2 edges: 2 bpermute + 1 u32 load +
// 2 cvt_pk + 4 fma (was ~14 instr + 2 loads). Loads/wave halve (32->16); 4 acc chains.
// Lanes 0-31 take even edge slots, 32-63 odd; lane q=lane&31 owns dims 4q..4q+3.
__global__ __launch_bounds__(512) void k_gat(const void* __restrict__ bg,
                                             const void* __restrict__ gam,
                                             const void* __restrict__ bet) {
    int wid = threadIdx.x >> 6, lane = threadIdx.x & 63;
    int n = blockIdx.x * 8 + wid;
    if (n >= NN) return;
    int bf = WS_FLAG[0];
    const int* col = WS_COL;
    const float* als = WS_ALS;
    int k0 = WS_ROWPTR[n], deg = WS_ROWPTR[n + 1] - k0;
    int hd = lane >> 4, eo = lane & 15;              // logit layout: lane = hd*16+eo
    int half = lane >> 5, q = lane & 31, hq = q >> 3; // gather layout: dims 4q..4q+3, head hq
    float aldh = WS_ALD[n * 4 + hd];
    const u32* hp32 = (const u32*)WS_HPB;
    const u64* h64 = (const u64*)WS_H;
    u64 hv = h64[(size_t)n * 32 + q];                // residual preload (halves duplicate)
    float se = 0.f, a0 = 0.f, a1 = 0.f, a2 = 0.f, a3 = 0.f;
    int wsel = hq * 16 + half;                        // bpermute base for weights

    for (int c = 0; c < deg; c += 32) {
        int i0 = c + eo, i1 = c + 16 + eo;
        int e0 = k0 + (i0 < deg ? i0 : 0);
        int e1 = k0 + (i1 < deg ? i1 : 0);
        int sc0 = col[e0];
        int sc1 = col[e1];
        float v0 = als[sc0 * 4 + hd] + aldh;
        float v1 = als[sc1 * 4 + hd] + aldh;
        v0 = v0 > 0.f ? v0 : 0.2f * v0;
        v1 = v1 > 0.f ? v1 : 0.2f * v1;
        float w0 = (i0 < deg) ? __expf(v0) : 0.f;    // logits bounded -> no max needed
        float w1 = (i1 < deg) ? __expf(v1) : 0.f;
        se += w0 + w1;
#pragma unroll
        for (int j = 0; j < 8; j++) {                // edge slots c + {2j+half}
            float wj = __shfl(w0, wsel + 2 * j);
            int   sj = __shfl(sc0, half + 2 * j);
            u32 v = hp32[(size_t)sj * 32 + q];
            f32x2 mlo = __builtin_amdgcn_cvt_pk_f32_fp8((int)v, false);
            f32x2 mhi = __builtin_amdgcn_cvt_pk_f32_fp8((int)v, true);
            a0 = fmaf(wj, mlo.x, a0);
            a1 = fmaf(wj, mlo.y, a1);
            a2 = fmaf(wj, mhi.x, a2);
            a3 = fmaf(wj, mhi.y, a3);
        }
        if (deg > c + 16) {                          // skip for deg<=16 (~47% of nodes)
#pragma unroll
            for (int j = 0; j < 8; j++) {            // edge slots c + 16 + {2j+half}
                float wj = __shfl(w1, wsel + 2 * j);
                int   sj = __shfl(sc1, half + 2 * j);
                u32 v = hp32[(size_t)sj * 32 + q];
                f32x2 mlo = __builtin_amdgcn_cvt_pk_f32_fp8((int)v, false);
                f32x2 mhi = __builtin_amdgcn_cvt_pk_f32_fp8((int)v, true);
                a0 = fmaf(wj, mlo.x, a0);
                a1 = fmaf(wj, mlo.y, a1);
                a2 = fmaf(wj, mhi.x, a2);
                a3 = fmaf(wj, mhi.y, a3);
            }
        }
    }
    // merge halves (each half accumulated alternate edge slots)
    a0 += __shfl_xor(a0, 32);
    a1 += __shfl_xor(a1, 32);
    a2 += __shfl_xor(a2, 32);
    a3 += __shfl_xor(a3, 32);
    se += __shfl_xor(se, 1);
    se += __shfl_xor(se, 2);
    se += __shfl_xor(se, 4);
    se += __shfl_xor(se, 8);
    float inv = 1.f / (se + 1e-16f);
    float invq = __shfl(inv, hq * 16);               // softmax denom for this lane's head
    int d0 = q * 4;
    u32 hlo = (u32)hv, hhi = (u32)(hv >> 32);
    float r0 = a0 * invq + ldf(bg, d0 + 0, bf) + b2f_lo(hlo);
    float r1 = a1 * invq + ldf(bg, d0 + 1, bf) + b2f_hi(hlo);
    float r2 = a2 * invq + ldf(bg, d0 + 2, bf) + b2f_lo(hhi);
    float r3 = a3 * invq + ldf(bg, d0 + 3, bf) + b2f_hi(hhi);
    float s1 = r0 + r1 + r2 + r3;
#pragma unroll
    for (int m = 1; m <= 32; m <<= 1) s1 += __shfl_xor(s1, m);
    float mu = s1 * (1.f / 256.f);                   // halves duplicated -> /256
    float e0f = r0 - mu, e1f = r1 - mu, e2f = r2 - mu, e3f = r3 - mu;
    float s2 = e0f * e0f + e1f * e1f + e2f * e2f + e3f * e3f;
#pragma unroll
    for (int m = 1; m <= 32; m <<= 1) s2 += __shfl_xor(s2, m);
    float rstd = rsqrtf(s2 * (1.f / 256.f) + 1e-5f);
    float y0 = e0f * rstd * ldf(gam, d0 + 0, bf) + ldf(bet, d0 + 0, bf);
    float y1 = e1f * rstd * ldf(gam, d0 + 1, bf) + ldf(bet, d0 + 1, bf);
    float y2 = e2f * rstd * ldf(gam, d0 + 2, bf) + ldf(bet, d0 + 2, bf);
    float y3 = e3f * rstd * ldf(gam, d0 + 3, bf) + ldf(bet, d0 + 3, bf);
    if (half == 0) {                                 // one copy writes (256B coalesced)
        u64 pk = (u64)f2bf(y0) | ((u64)f2bf(y1) << 16)
               | ((u64)f2bf(y2) << 32) | ((u64)f2bf(y3) << 48);
        ((u64*)WS_H)[(size_t)n * 32 + q] = pk;
    }
}

// ---------------- pooling driven by the ACTUAL node2graph input ----------------
__global__ __launch_bounds__(128) void k_pool(const int* __restrict__ n2g) {
    int j = threadIdx.x;
    int wide = WS_FLAG[1];
    int n0 = blockIdx.x * 128;
    int n1 = n0 + 128; if (n1 > NN) n1 = NN;
    float runs = 0.f, runm = -3.4e38f;
    int rung = -1, runc = 0;
    for (int n = n0; n < n1; n++) {
        int g = ldint(n2g, n, wide);
        if (g != rung) {
            if (rung >= 0 && (u32)rung < NG) {
                atomicAdd(&WS_GSUM[rung * 128 + j], runs);
                atomicMax(&WS_GKEY[rung * 128 + j], fkey(runm));
                if (j == 0) atomicAdd(&WS_GCNT[rung], runc);
            }
            rung = g; runs = 0.f; runm = -3.4e38f; runc = 0;
        }
        float v = b2f(WS_H[(size_t)n * 128 + j]);
        runs += v;
        runm = fmaxf(runm, v);
        runc++;
    }
    if (rung >= 0 && (u32)rung < NG) {
        atomicAdd(&WS_GSUM[rung * 128 + j], runs);
        atomicMax(&WS_GKEY[rung * 128 + j], fkey(runm));
        if (j == 0) atomicAdd(&WS_GCNT[rung], runc);
    }
}

// ---------------- head MLP: 256 threads per graph; FP32 output ----------------
__global__ __launch_bounds__(256) void k_head(const void* __restrict__ Wq1,
                                              const void* __restrict__ bq1,
                                              const void* __restrict__ gq,
                                              const void* __restrict__ beq,
                                              const void* __restrict__ Wq2,
                                              const void* __restrict__ bq2,
                                              float* __restrict__ out) {
    __shared__ float sem[256];
    __shared__ float sp[128];
    __shared__ float red[4];
    int g = blockIdx.x, t = threadIdx.x;
    int bf = WS_FLAG[0];
    float cnt = fmaxf((float)WS_GCNT[g], 1.f);
    if (t < 128) sem[t] = WS_GSUM[g * 128 + t] / cnt;
    else         sem[t] = funkey(WS_GKEY[g * 128 + (t - 128)]);
    __syncthreads();
    float a = 0.f;
    if (t < 128) {
        a = ldf(bq1, t, bf);
        for (int k = 0; k < 256; k++) a = fmaf(sem[k], ldf(Wq1, k * 128 + t, bf), a);
    }
    int lane = t & 63, wv = t >> 6;
    float s1 = (t < 128) ? a : 0.f;
#pragma unroll
    for (int m = 1; m <= 32; m <<= 1) s1 += __shfl_xor(s1, m);
    if (lane == 0) red[wv] = s1;
    __syncthreads();
    float mu = (red[0] + red[1]) * (1.f / 128.f);
    float d = (t < 128) ? (a - mu) : 0.f;
    float s2 = d * d;
#pragma unroll
    for (int m = 1; m <= 32; m <<= 1) s2 += __shfl_xor(s2, m);
    __syncthreads();
    if (lane == 0) red[wv] = s2;
    __syncthreads();
    float var = (red[0] + red[1]) * (1.f / 128.f);
    if (t < 128) {
        float p = d * rsqrtf(var + 1e-5f) * ldf(gq, t, bf) + ldf(beq, t, bf);
        sp[t] = 0.5f * p * (1.0f + erff(p * 0.70710678118654752f));
    }
    __syncthreads();
    float o = ldf(bq2, t, bf);
    for (int k = 0; k < 128; k++)
        o = fmaf(sp[k], ldf(Wq2, k * 256 + t, bf), o);
    out[g * 256 + t] = o;
}

extern "C" void kernel_launch(void* const* d_in, const int* in_sizes, int n_in,
                              void* d_out, int out_size, void* d_ws, size_t ws_size,
                              hipStream_t stream) {
    const void* x   = d_in[0];
    const int* ei   = (const int*)d_in[1];
    const int* n2g  = (const int*)d_in[2];
    const void* Wp  = d_in[3];
    const void* bp  = d_in[4];
    const void* Wq1 = d_in[5];
    const void* bq1 = d_in[6];
    const void* gq  = d_in[7];
    const void* beq = d_in[8];
    const void* Wq2 = d_in[9];
    const void* bq2 = d_in[10];
    const void* Wg0 = d_in[11];
    const void* as0 = d_in[12];
    const void* ad0 = d_in[13];
    const void* bg0 = d_in[14];
    const void* g0  = d_in[15];
    const void* be0 = d_in[16];
    const void* Wg1 = d_in[17];
    const void* as1 = d_in[18];
    const void* ad1 = d_in[19];
    const void* bg1 = d_in[20];
    const void* g1  = d_in[21];
    const void* be1 = d_in[22];
    (void)d_ws; (void)ws_size; (void)in_sizes; (void)n_in; (void)out_size;

    k_zero<<<(NN + 255) / 256, 256, 0, stream>>>(x, ei);

    // CSR build: global-atomic degree + scan + fill (no bucket staging)
    k_deg<<<(ETOT + EPB - 1) / EPB, 256, 0, stream>>>(ei);
    k_scan1<<<SCANB, 1024, 0, stream>>>();
    k_fin<<<SCANB, 1024, 0, stream>>>();
    k_fill<<<(ETOT + EPB - 1) / EPB, 256, 0, stream>>>(ei);

    // node MLP
    k_proj<<<2048, 128, 0, stream>>>(x, Wp, bp);

    // layer 0
    k_gemm<<<1024, 256, 0, stream>>>(Wg0, as0, ad0);
    k_gat<<<(NN + 7) / 8, 512, 0, stream>>>(bg0, g0, be0);
    // layer 1
    k_gemm<<<1024, 256, 0, stream>>>(Wg1, as1, ad1);
    k_gat<<<(NN + 7) / 8, 512, 0, stream>>>(bg1, g1, be1);

    // pooling + head
    k_pool<<<(NN + 127) / 128, 128, 0, stream>>>(n2g);
    k_head<<<NG, 256, 0, stream>>>(Wq1, bq1, gq, beq, Wq2, bq2, (float*)d_out);
}

// Round 3
// 543.232 us; speedup vs baseline: 1.3377x; 1.3377x over previous
//
#include <hip/hip_runtime.h>

typedef unsigned short u16;
typedef unsigned char u8;
typedef unsigned int u32;
typedef unsigned long long u64;
typedef short short8 __attribute__((ext_vector_type(8)));
typedef float f32x4 __attribute__((ext_vector_type(4)));
typedef float f32x2 __attribute__((ext_vector_type(2)));

#define NN   100000
#define EE   1600000
#define ETOT (EE + NN)
#define NG   64
#define WSTR 136   // padded LDS row stride in bf16 elems (128 + 8)
#define SCANB 98   // ceil(NN / 1024)
#define NB   98    // dst buckets of 1024 nodes
#define BCAP 24576 // per-bucket edge capacity (mean 17.4k, +54 sigma)
#define OCAP 262144
#define EPB  4096  // edges per block in k_bucket

// ---------------- static device workspace ----------------
constexpr size_t AL256(size_t x) { return (x + 255) & ~(size_t)255; }
constexpr size_t OFF_FLAG   = 0;                                   // [0]=bf16 [1]=wide [2]=OCNT
constexpr size_t OFF_BSUM   = AL256(OFF_FLAG + 256);
constexpr size_t OFF_BCNT   = AL256(OFF_BSUM + 128 * 4);
constexpr size_t OFF_ROWPTR = AL256(OFF_BCNT + 128 * 4);
constexpr size_t OFF_DEG    = AL256(OFF_ROWPTR + (size_t)(NN + 1) * 4);  // overflow counts
constexpr size_t OFF_COL    = AL256(OFF_DEG + (size_t)NN * 4);
constexpr size_t OFF_ALS    = AL256(OFF_COL + (size_t)ETOT * 4);
constexpr size_t OFF_ALD    = AL256(OFF_ALS + (size_t)NN * 4 * 4);
constexpr size_t OFF_GSUM   = AL256(OFF_ALD + (size_t)NN * 4 * 4);
constexpr size_t OFF_GKEY   = AL256(OFF_GSUM + (size_t)NG * 128 * 4);
constexpr size_t OFF_GCNT   = AL256(OFF_GKEY + (size_t)NG * 128 * 4);
constexpr size_t OFF_H      = AL256(OFF_GCNT + (size_t)NG * 4);          // bf16 h
constexpr size_t OFF_HPB    = AL256(OFF_H + (size_t)NN * 128 * 2);       // fp8-e4m3 hp
constexpr size_t OFF_EBUF   = AL256(OFF_HPB + (size_t)NN * 128 * 1);     // bucketed edges
constexpr size_t OFF_OBUF   = AL256(OFF_EBUF + (size_t)NB * BCAP * 8);   // overflow edges
constexpr size_t WS_TOTAL   = AL256(OFF_OBUF + (size_t)OCAP * 8);

__device__ u64 g_ws[WS_TOTAL / 8];

__device__ __forceinline__ char* wsp() { return (char*)g_ws; }
#define WS_FLAG   ((int*)(wsp() + OFF_FLAG))
#define WS_BSUM   ((int*)(wsp() + OFF_BSUM))
#define WS_BCNT   ((int*)(wsp() + OFF_BCNT))
#define WS_ROWPTR ((int*)(wsp() + OFF_ROWPTR))
#define WS_DEG    ((int*)(wsp() + OFF_DEG))
#define WS_COL    ((int*)(wsp() + OFF_COL))
#define WS_ALS    ((float*)(wsp() + OFF_ALS))
#define WS_ALD    ((float*)(wsp() + OFF_ALD))
#define WS_GSUM   ((float*)(wsp() + OFF_GSUM))
#define WS_GKEY   ((u32*)(wsp() + OFF_GKEY))
#define WS_GCNT   ((int*)(wsp() + OFF_GCNT))
#define WS_H      ((u16*)(wsp() + OFF_H))
#define WS_HPB    ((u8*)(wsp() + OFF_HPB))
#define WS_EBUF   ((u64*)(wsp() + OFF_EBUF))
#define WS_OBUF   ((u64*)(wsp() + OFF_OBUF))

__device__ __forceinline__ float b2f(u16 u) { return __uint_as_float(((u32)u) << 16); }
__device__ __forceinline__ float b2f_lo(u32 u) { return __uint_as_float(u << 16); }
__device__ __forceinline__ float b2f_hi(u32 u) { return __uint_as_float(u & 0xffff0000u); }
__device__ __forceinline__ u16 f2bf(float f) {
    u32 u = __float_as_uint(f);
    return (u16)((u + 0x7fffu + ((u >> 16) & 1u)) >> 16);
}
__device__ __forceinline__ float ldf(const void* p, int i, int bf) {
    return bf ? b2f(((const u16*)p)[i]) : ((const float*)p)[i];
}
__device__ __forceinline__ int ldint(const int* p, long long i, int wide) {
    return wide ? p[i * 2] : p[(size_t)i];
}
__device__ __forceinline__ u32 fkey(float f) {
    u32 u = __float_as_uint(f);
    return (u >> 31) ? ~u : (u | 0x80000000u);
}
__device__ __forceinline__ float funkey(u32 k) {
    u32 u = (k & 0x80000000u) ? (k & 0x7fffffffu) : ~k;
    return __uint_as_float(u);
}

// ---------------- zero scratch + dtype probes (fused) ----------------
__global__ __launch_bounds__(256) void k_zero(const void* __restrict__ x,
                                              const int* __restrict__ ei) {
    if (blockIdx.x == 0 && threadIdx.x < 64) {
        int t = threadIdx.x;
        const u16* p = (const u16*)x;
        u16 u = p[t * 2];
        int e = (u >> 7) & 0xff;
        int ok = ((u & 0x7fffu) == 0) || (e >= 0x60 && e <= 0x9f);
        u64 m1 = __ballot(ok);
        int z = (ei[t * 2 + 1] == 0);
        u64 m2 = __ballot(z);
        if (t == 0) {
            WS_FLAG[0] = (__popcll(m1) >= 48) ? 1 : 0;
            WS_FLAG[1] = (__popcll(m2) >= 56) ? 1 : 0;
        }
    }
    if (blockIdx.x == 0 && threadIdx.x == 64) WS_FLAG[2] = 0;  // overflow count
    int i = blockIdx.x * 256 + threadIdx.x;
    if (i < NN) WS_DEG[i] = 0;
    if (i < NG * 128) { WS_GSUM[i] = 0.f; WS_GKEY[i] = 0u; }
    if (i < NG) WS_GCNT[i] = 0;
    if (i < NB) WS_BCNT[i] = 0;
}

// ---- CSR build phase 1: bucket edges by dst>>10, block-level reservations ----
__global__ __launch_bounds__(256) void k_bucket(const int* __restrict__ ei) {
    __shared__ int lcnt[NB], lbase[NB], lcur[NB];
    int t = threadIdx.x;
    int wide = WS_FLAG[1];
    for (int i = t; i < NB; i += 256) { lcnt[i] = 0; lcur[i] = 0; }
    __syncthreads();
    int e0 = blockIdx.x * EPB + t;
    int sA[16], dA[16];
#pragma unroll
    for (int j = 0; j < 16; j++) {
        int e = e0 + j * 256;
        int s = -1, d = 0;
        if (e < ETOT) {
            if (e < EE) {
                if (wide) { s = ((const int2*)ei)[e].x; d = ((const int2*)ei)[(size_t)EE + e].x; }
                else      { s = ei[e];                  d = ei[(size_t)EE + e]; }
            } else { s = e - EE; d = s; }
            if ((u32)s >= NN || (u32)d >= NN) s = -1;
        }
        sA[j] = s; dA[j] = d;
        if (s >= 0) atomicAdd(&lcnt[d >> 10], 1);
    }
    __syncthreads();
    for (int i = t; i < NB; i += 256)
        lbase[i] = atomicAdd(&WS_BCNT[i], lcnt[i]);
    __syncthreads();
    u64* ebuf = WS_EBUF;
#pragma unroll
    for (int j = 0; j < 16; j++) {
        int s = sA[j], d = dA[j];
        if (s < 0) continue;
        int b = d >> 10;
        int r = atomicAdd(&lcur[b], 1);
        int slot = lbase[b] + r;
        u64 pk = ((u64)(u32)d << 32) | (u32)s;
        if (slot < BCAP) {
            ebuf[(size_t)b * BCAP + slot] = pk;
        } else {  // overflow path (never taken for uniform data; keeps correctness)
            int o = atomicAdd(&WS_FLAG[2], 1);
            if (o < OCAP) {
                WS_OBUF[o] = pk;
                atomicAdd(&WS_DEG[d], 1);   // DEG carries overflow counts only
            }
        }
    }
}

// ---- CSR phase 2: scan block b IS bucket b — fused histogram + local scan ----
__global__ __launch_bounds__(1024) void k_scan1() {
    __shared__ int sdat[1024];
    __shared__ int hist[1024];
    int b = blockIdx.x, t = threadIdx.x;
    hist[t] = 0;
    __syncthreads();
    int bc = WS_BCNT[b]; if (bc > BCAP) bc = BCAP;
    const u64* eb = WS_EBUF + (size_t)b * BCAP;
    for (int i = t; i < bc; i += 1024) {
        int d = (int)(eb[i] >> 32);
        atomicAdd(&hist[d & 1023], 1);
    }
    __syncthreads();
    int i = b * 1024 + t;
    int v = (i < NN) ? (WS_DEG[i] + hist[t]) : 0;   // deg = bucket hist + overflow
    sdat[t] = v;
    __syncthreads();
    for (int off = 1; off < 1024; off <<= 1) {
        int u = 0;
        if (t >= off) u = sdat[t - off];
        __syncthreads();
        if (t >= off) sdat[t] += u;
        __syncthreads();
    }
    if (i < NN) WS_ROWPTR[i] = sdat[t] - v;   // local exclusive prefix
    if (t == 1023) WS_BSUM[b] = sdat[1023];
}

// ---- CSR phase 3: finalize rowptr (BSUM scan in-block) + place via LDS cursors ----
__global__ __launch_bounds__(256) void k_place() {
    __shared__ int cur[1024];
    __shared__ int sb[128];
    int b = blockIdx.x, t = threadIdx.x;
    if (t < 128) sb[t] = (t < SCANB) ? WS_BSUM[t] : 0;
    __syncthreads();
    for (int off = 1; off < 128; off <<= 1) {
        int u = 0;
        if (t < 128 && t >= off) u = sb[t - off];
        __syncthreads();
        if (t < 128 && t >= off) sb[t] += u;
        __syncthreads();
    }
    int add = (b > 0) ? sb[b - 1] : 0;
    int n0 = b << 10;
    for (int i = t; i < 1024; i += 256) {
        int n = n0 + i;
        int r = 0;
        if (n < NN) {
            r = WS_ROWPTR[n] + add;
            WS_ROWPTR[n] = r;       // finalize global rowptr
        }
        cur[i] = r;                 // LDS cursor
    }
    if (b == 0 && t == 0) WS_ROWPTR[NN] = sb[127];  // grand total
    __syncthreads();
    int bc = WS_BCNT[b]; if (bc > BCAP) bc = BCAP;
    const u64* eb = WS_EBUF + (size_t)b * BCAP;
    for (int i = t; i < bc; i += 256) {
        u64 pk = eb[i];
        int d = (int)(pk >> 32), s = (int)(pk & 0xffffffffu);
        int pos = atomicAdd(&cur[d & 1023], 1);
        WS_COL[pos] = s;
    }
    // overflow sweep (cnt==0 in practice; same LDS cursors keep it correct)
    int cnt = WS_FLAG[2]; if (cnt > OCAP) cnt = OCAP;
    for (int i = t; i < cnt; i += 256) {
        u64 pk = WS_OBUF[i];
        int d = (int)(pk >> 32);
        if ((d >> 10) == b) {
            int pos = atomicAdd(&cur[d & 1023], 1);
            WS_COL[pos] = (int)(pk & 0xffffffffu);
        }
    }
}

// ---------------- node feature MLP: h = gelu(x @ Wp + bp), bf16 out ----------------
__global__ __launch_bounds__(128) void k_proj(const void* __restrict__ x,
                                              const void* __restrict__ Wp,
                                              const void* __restrict__ bp) {
    __shared__ float sW[16 * 128];
    int t = threadIdx.x;
    int bf = WS_FLAG[0];
    for (int i = t; i < 16 * 128; i += 128) sW[i] = ldf(Wp, i, bf);
    __syncthreads();
    float bj = ldf(bp, t, bf);
    for (int n = blockIdx.x; n < NN; n += gridDim.x) {
        float acc = bj;
#pragma unroll
        for (int k = 0; k < 16; k++)
            acc = fmaf(ldf(x, n * 16 + k, bf), sW[k * 128 + t], acc);
        float g = 0.5f * acc * (1.0f + erff(acc * 0.70710678118654752f));
        WS_H[(size_t)n * 128 + t] = f2bf(g);
    }
}

// --- hp = h @ Wg via MFMA 16x16x32 bf16; fp8-e4m3 hp out; fused als/ald ---
// R3: even/odd column pairing (tile0 = col n0+2*m16, tile1 = col n0+2*m16+1) so the
// epilogue's cvt_pk_fp8 bytes land adjacent -> one aligned u16 store (was 2 byte stores).
// als/ald reduction unchanged: union of covered columns is still n0..n0+31.
__global__ __launch_bounds__(256) void k_gemm(const void* __restrict__ Wg,
                                              const void* __restrict__ a_s,
                                              const void* __restrict__ a_d) {
    __shared__ __align__(16) u16 sWt[128 * WSTR];   // W transposed, padded
    __shared__ __align__(16) u16 sH[16 * WSTR];     // 16 H rows (bf16), padded
    int t = threadIdx.x;
    int bf = WS_FLAG[0];
    for (int idx = t; idx < 128 * 128; idx += 256) {
        int k = idx >> 7, n = idx & 127;
        sWt[n * WSTR + k] = bf ? ((const u16*)Wg)[idx] : f2bf(((const float*)Wg)[idx]);
    }
    __syncthreads();
    int wv = t >> 6, lane = t & 63;
    int n0 = wv * 32;                 // wave wv owns cols 32wv..32wv+31 == head wv
    int quad = lane >> 4, m16 = lane & 15;
    int ce = n0 + 2 * m16;            // even/odd column pair owned by this lane
    float as0v = ldf(a_s, ce, bf),     as1v = ldf(a_s, ce + 1, bf);
    float ad0v = ldf(a_d, ce, bf),     ad1v = ldf(a_d, ce + 1, bf);
    short8 bfr[2][4];
#pragma unroll
    for (int nt = 0; nt < 2; nt++) {
        int n = ce + nt;              // tile0: even col, tile1: odd col
#pragma unroll
        for (int ks = 0; ks < 4; ks++)
            bfr[nt][ks] = *(const short8*)&sWt[n * WSTR + ks * 32 + quad * 8];
    }
    u8* hp = WS_HPB;
    const u32* h32 = (const u32*)WS_H;
    u32* sH32 = (u32*)sH;
    for (int m0 = blockIdx.x * 16; m0 < NN; m0 += gridDim.x * 16) {
        __syncthreads();
        for (int idx = t; idx < 16 * 64; idx += 256) {
            int r = idx >> 6, c2 = idx & 63;
            sH32[r * 68 + c2] = h32[(size_t)(m0 + r) * 64 + c2];  // 68 = WSTR/2
        }
        __syncthreads();
        f32x4 acc0 = {0.f, 0.f, 0.f, 0.f};
        f32x4 acc1 = {0.f, 0.f, 0.f, 0.f};
#pragma unroll
        for (int ks = 0; ks < 4; ks++) {
            short8 af = *(const short8*)&sH[m16 * WSTR + ks * 32 + quad * 8];
            acc0 = __builtin_amdgcn_mfma_f32_16x16x32_bf16(af, bfr[0][ks], acc0, 0, 0, 0);
            acc1 = __builtin_amdgcn_mfma_f32_16x16x32_bf16(af, bfr[1][ks], acc1, 0, 0, 0);
        }
        // D: row = quad*4 + reg; acc0 = even col, acc1 = odd col (adjacent bytes)
#pragma unroll
        for (int r = 0; r < 4; r++) {
            size_t row = (size_t)(m0 + quad * 4 + r) * 128;
            u32 pk8 = (u32)__builtin_amdgcn_cvt_pk_fp8_f32(acc0[r], acc1[r], 0, false);
            *(u16*)&hp[row + ce] = (u16)(pk8 & 0xffffu);
            float ps = acc0[r] * as0v + acc1[r] * as1v;
            float pd = acc0[r] * ad0v + acc1[r] * ad1v;
#pragma unroll
            for (int m = 1; m <= 8; m <<= 1) {
                ps += __shfl_xor(ps, m);
                pd += __shfl_xor(pd, m);
            }
            if (m16 == 0) {
                int nrow = m0 + quad * 4 + r;
                WS_ALS[nrow * 4 + wv] = ps;
                WS_ALD[nrow * 4 + wv] = pd;
            }
        }
    }
}

// ------- GAT: 1 node/wave, single-phase 32-slot logits + gather bursts -------
// R1 structure (proven 88 µs, 0 bank conflicts): scalar-base gather addressing via
// readlane, 1 bpermute/edge for the weight. R3: skip the second 16-burst when
// deg <= 16 (~47% of nodes) — wave-uniform branch, saves ~23% of gather issue work.
__global__ __launch_bounds__(512) void k_gat(const void* __restrict__ bg,
                                             const void* __restrict__ gam,
                                             const void* __restrict__ bet) {
    int wid = threadIdx.x >> 6, lane = threadIdx.x & 63;
    int n = blockIdx.x * 8 + wid;
    if (n >= NN) return;
    int bf = WS_FLAG[0];
    const int* col = WS_COL;
    const float* als = WS_ALS;
    int k0 = WS_ROWPTR[n], deg = WS_ROWPTR[n + 1] - k0;
    int hd = lane >> 4, eo = lane & 15;   // head-major: lane's dims 2*lane,2*lane+1 in head hd
    float aldh = WS_ALD[n * 4 + hd];
    const u16* hp16 = (const u16*)WS_HPB;  // 2 fp8 per u16: bytes 2*lane, 2*lane+1
    u32* h32 = (u32*)WS_H;
    u32 hv = h32[(size_t)n * 64 + lane];   // residual preload: own row -> in-place safe
    int base48 = lane & 48;

    // logits for 32 slots in one shot (deg <= 32 covers ~all nodes, Poisson(17))
    int i0 = eo, i1 = eo + 16;
    int e0 = k0 + (i0 < deg ? i0 : 0);
    int e1 = k0 + (i1 < deg ? i1 : 0);
    int sc0 = col[e0];
    int sc1 = col[e1];
    float v0 = als[sc0 * 4 + hd] + aldh;
    float v1 = als[sc1 * 4 + hd] + aldh;
    v0 = v0 > 0.f ? v0 : 0.2f * v0;
    v1 = v1 > 0.f ? v1 : 0.2f * v1;
    float w0 = (i0 < deg) ? __expf(v0) : 0.f;   // logits bounded -> no max needed
    float w1 = (i1 < deg) ? __expf(v1) : 0.f;
    float se = w0 + w1;
    float a0 = 0.f, a1 = 0.f;

    // straight-line 16-deep gather burst: no branches -> loads hoist & stay in flight
#pragma unroll
    for (int j = 0; j < 16; j++) {
        float wj = __shfl(w0, base48 + j);                  // per-head weight
        int   sj = __builtin_amdgcn_readlane(sc0, j);       // wave-uniform src id
        u16 pv = hp16[(size_t)sj * 64 + lane];
        f32x2 mv = __builtin_amdgcn_cvt_pk_f32_fp8((int)pv, false);
        a0 = fmaf(wj, mv.x, a0);
        a1 = fmaf(wj, mv.y, a1);
    }
    if (deg > 16) {                  // wave-uniform skip: ~47% of nodes avoid burst 2
#pragma unroll
        for (int j = 0; j < 16; j++) {
            float wj = __shfl(w1, base48 + j);
            int   sj = __builtin_amdgcn_readlane(sc1, j);
            u16 pv = hp16[(size_t)sj * 64 + lane];
            f32x2 mv = __builtin_amdgcn_cvt_pk_f32_fp8((int)pv, false);
            a0 = fmaf(wj, mv.x, a0);
            a1 = fmaf(wj, mv.y, a1);
        }
    }

    if (__builtin_expect(deg > 32, 0)) {   // rare tail (~4e-4 of nodes)
        for (int c = 32; c < deg; c += 16) {
            int i = c + eo;
            float w = 0.f; int scol = 0;
            if (i < deg) {
                scol = col[k0 + i];
                float v = als[scol * 4 + hd] + aldh;
                v = v > 0.f ? v : 0.2f * v;
                w = __expf(v);
            }
            se += w;
            int rem = deg - c; if (rem > 16) rem = 16;
            for (int j = 0; j < rem; j++) {
                float wj = __shfl(w, base48 + j);
                int sj = __shfl(scol, base48 + j);
                u16 pv = hp16[(size_t)sj * 64 + lane];
                f32x2 mv = __builtin_amdgcn_cvt_pk_f32_fp8((int)pv, false);
                a0 = fmaf(wj, mv.x, a0);
                a1 = fmaf(wj, mv.y, a1);
            }
        }
    }

    se += __shfl_xor(se, 1);
    se += __shfl_xor(se, 2);
    se += __shfl_xor(se, 4);
    se += __shfl_xor(se, 8);
    float inv = 1.f / (se + 1e-16f);
    int d0 = lane * 2, d1 = d0 + 1;
    float r0 = a0 * inv + ldf(bg, d0, bf) + b2f_lo(hv);
    float r1 = a1 * inv + ldf(bg, d1, bf) + b2f_hi(hv);
    float s1 = r0 + r1;
#pragma unroll
    for (int m = 1; m <= 32; m <<= 1) s1 += __shfl_xor(s1, m);
    float mu = s1 * (1.f / 128.f);
    float e0f = r0 - mu, e1f = r1 - mu;
    float s2 = e0f * e0f + e1f * e1f;
#pragma unroll
    for (int m = 1; m <= 32; m <<= 1) s2 += __shfl_xor(s2, m);
    float rstd = rsqrtf(s2 * (1.f / 128.f) + 1e-5f);
    float y0 = e0f * rstd * ldf(gam, d0, bf) + ldf(bet, d0, bf);
    float y1 = e1f * rstd * ldf(gam, d1, bf) + ldf(bet, d1, bf);
    h32[(size_t)n * 64 + lane] = (u32)f2bf(y0) | ((u32)f2bf(y1) << 16);
}

// ---------------- pooling driven by the ACTUAL node2graph input ----------------
__global__ __launch_bounds__(128) void k_pool(const int* __restrict__ n2g) {
    int j = threadIdx.x;
    int wide = WS_FLAG[1];
    int n0 = blockIdx.x * 128;
    int n1 = n0 + 128; if (n1 > NN) n1 = NN;
    float runs = 0.f, runm = -3.4e38f;
    int rung = -1, runc = 0;
    for (int n = n0; n < n1; n++) {
        int g = ldint(n2g, n, wide);
        if (g != rung) {
            if (rung >= 0 && (u32)rung < NG) {
                atomicAdd(&WS_GSUM[rung * 128 + j], runs);
                atomicMax(&WS_GKEY[rung * 128 + j], fkey(runm));
                if (j == 0) atomicAdd(&WS_GCNT[rung], runc);
            }
            rung = g; runs = 0.f; runm = -3.4e38f; runc = 0;
        }
        float v = b2f(WS_H[(size_t)n * 128 + j]);
        runs += v;
        runm = fmaxf(runm, v);
        runc++;
    }
    if (rung >= 0 && (u32)rung < NG) {
        atomicAdd(&WS_GSUM[rung * 128 + j], runs);
        atomicMax(&WS_GKEY[rung * 128 + j], fkey(runm));
        if (j == 0) atomicAdd(&WS_GCNT[rung], runc);
    }
}

// ---------------- head MLP: 256 threads per graph; FP32 output ----------------
__global__ __launch_bounds__(256) void k_head(const void* __restrict__ Wq1,
                                              const void* __restrict__ bq1,
                                              const void* __restrict__ gq,
                                              const void* __restrict__ beq,
                                              const void* __restrict__ Wq2,
                                              const void* __restrict__ bq2,
                                              float* __restrict__ out) {
    __shared__ float sem[256];
    __shared__ float sp[128];
    __shared__ float red[4];
    int g = blockIdx.x, t = threadIdx.x;
    int bf = WS_FLAG[0];
    float cnt = fmaxf((float)WS_GCNT[g], 1.f);
    if (t < 128) sem[t] = WS_GSUM[g * 128 + t] / cnt;
    else         sem[t] = funkey(WS_GKEY[g * 128 + (t - 128)]);
    __syncthreads();
    float a = 0.f;
    if (t < 128) {
        a = ldf(bq1, t, bf);
        for (int k = 0; k < 256; k++) a = fmaf(sem[k], ldf(Wq1, k * 128 + t, bf), a);
    }
    int lane = t & 63, wv = t >> 6;
    float s1 = (t < 128) ? a : 0.f;
#pragma unroll
    for (int m = 1; m <= 32; m <<= 1) s1 += __shfl_xor(s1, m);
    if (lane == 0) red[wv] = s1;
    __syncthreads();
    float mu = (red[0] + red[1]) * (1.f / 128.f);
    float d = (t < 128) ? (a - mu) : 0.f;
    float s2 = d * d;
#pragma unroll
    for (int m = 1; m <= 32; m <<= 1) s2 += __shfl_xor(s2, m);
    __syncthreads();
    if (lane == 0) red[wv] = s2;
    __syncthreads();
    float var = (red[0] + red[1]) * (1.f / 128.f);
    if (t < 128) {
        float p = d * rsqrtf(var + 1e-5f) * ldf(gq, t, bf) + ldf(beq, t, bf);
        sp[t] = 0.5f * p * (1.0f + erff(p * 0.70710678118654752f));
    }
    __syncthreads();
    float o = ldf(bq2, t, bf);
    for (int k = 0; k < 128; k++)
        o = fmaf(sp[k], ldf(Wq2, k * 256 + t, bf), o);
    out[g * 256 + t] = o;
}

extern "C" void kernel_launch(void* const* d_in, const int* in_sizes, int n_in,
                              void* d_out, int out_size, void* d_ws, size_t ws_size,
                              hipStream_t stream) {
    const void* x   = d_in[0];
    const int* ei   = (const int*)d_in[1];
    const int* n2g  = (const int*)d_in[2];
    const void* Wp  = d_in[3];
    const void* bp  = d_in[4];
    const void* Wq1 = d_in[5];
    const void* bq1 = d_in[6];
    const void* gq  = d_in[7];
    const void* beq = d_in[8];
    const void* Wq2 = d_in[9];
    const void* bq2 = d_in[10];
    const void* Wg0 = d_in[11];
    const void* as0 = d_in[12];
    const void* ad0 = d_in[13];
    const void* bg0 = d_in[14];
    const void* g0  = d_in[15];
    const void* be0 = d_in[16];
    const void* Wg1 = d_in[17];
    const void* as1 = d_in[18];
    const void* ad1 = d_in[19];
    const void* bg1 = d_in[20];
    const void* g1  = d_in[21];
    const void* be1 = d_in[22];
    (void)d_ws; (void)ws_size; (void)in_sizes; (void)n_in; (void)out_size;

    k_zero<<<(NN + 255) / 256, 256, 0, stream>>>(x, ei);

    // CSR build: bucketed, LDS-localized atomics; 3 kernels
    k_bucket<<<(ETOT + EPB - 1) / EPB, 256, 0, stream>>>(ei);
    k_scan1<<<SCANB, 1024, 0, stream>>>();
    k_place<<<NB, 256, 0, stream>>>();

    // node MLP
    k_proj<<<2048, 128, 0, stream>>>(x, Wp, bp);

    // layer 0
    k_gemm<<<1024, 256, 0, stream>>>(Wg0, as0, ad0);
    k_gat<<<(NN + 7) / 8, 512, 0, stream>>>(bg0, g0, be0);
    // layer 1
    k_gemm<<<1024, 256, 0, stream>>>(Wg1, as1, ad1);
    k_gat<<<(NN + 7) / 8, 512, 0, stream>>>(bg1, g1, be1);

    // pooling + head
    k_pool<<<(NN + 127) / 128, 128, 0, stream>>>(n2g);
    k_head<<<NG, 256, 0, stream>>>(Wq1, bq1, gq, beq, Wq2, bq2, (float*)d_out);
}